// Round 8
// baseline (306.676 us; speedup 1.0000x reference)
//
#include <hip/hip_runtime.h>

// CIN fused kernel, round 8: mfma_f32_32x32x16_f16, low-pressure pipelined K-loop.
// r7 diagnosis: 84 arch regs forced loads to issue-and-wait inside each step
// (MfmaUtil 38%, wall = 2.6x MFMA busy). Fix: (1) triangular mask + 2x folded
// into fprep (prep zeroes j<=i and j>=39 rows for layer 0) -> no mask VALU,
// no static-index constraint; (2) h read from LDS per step (runtime index OK
// now) -> no 32-reg hreg; (3) explicit 1-step prefetch rotation (load Bf/h/xv
// for s+1, MFMA step s) -> >=129cy issue-to-use distance; (4) layer-0 sparse
// chunk list as flat __constant__ schedule so all layers share the pipelined
// loop. Live ~120 regs -> launch_bounds(256,3), 12 waves/CU, spill-free.
// GEMM: M = B*16 (m = batch*16+d), N = 128, K = i*64+j (layer-0 zero-padded).
// Wave (mg,ng): 2 m-tiles (batches mg*4..+4) x 2 n-tiles (cols ng*64..+64).

#define F0N 39
#define NC16 156                              // K/16 per layer
#define LAYER_HALVES (NC16 * 4 * 64 * 8)      // 319488 f16 per layer

typedef _Float16 half8 __attribute__((ext_vector_type(8)));
typedef float f32x16 __attribute__((ext_vector_type(16)));

// Layer-0 useful chunks (c16 = 4*i + q, chunk q covers j in [16q,16q+16)):
// q=0: i<=14, q=1: i<=30, q=2: i<=37 -> 84 steps; entry [84] = pad for prefetch.
__constant__ int l0_sched[85] = {
    0,1,2, 4,5,6, 8,9,10, 12,13,14, 16,17,18, 20,21,22, 24,25,26, 28,29,30,
    32,33,34, 36,37,38, 40,41,42, 44,45,46, 48,49,50, 52,53,54, 56,57,58,
    61,62, 65,66, 69,70, 73,74, 77,78, 81,82, 85,86, 89,90, 93,94, 97,98,
    101,102, 105,106, 109,110, 113,114, 117,118, 121,122,
    126, 130, 134, 138, 142, 146, 150, 150};

// ---- prep: swizzle filters into 32x32x16 B-fragment order, f16 ----
// fprep[l][c16][nt][lane][reg] = F_l[row(kg), nt*32 + (lane&31)],
// kg = c16*16 + (lane>>5)*8 + reg. Layer 0: row = i*39+j (i=kg>>6, j=kg&63),
// value = 2*F0 if j>i && j<39 else 0  (triangular mask + x2 folded in).
__global__ void prep_kernel(const float* __restrict__ f0,
                            const float* __restrict__ f1,
                            const float* __restrict__ f2,
                            _Float16* __restrict__ fprep) {
    int blk  = blockIdx.x;            // l*NC16 + c16
    int l    = blk / NC16;
    int c16  = blk - l * NC16;
    int t    = threadIdx.x;
    int nt   = t >> 6;
    int lane = t & 63;
    int hf   = lane >> 5;
    int n    = nt * 32 + (lane & 31);
    const float* f = (l == 0) ? f0 : ((l == 1) ? f1 : f2);
    half8 v;
    #pragma unroll
    for (int reg = 0; reg < 8; ++reg) {
        int kg = c16 * 16 + hf * 8 + reg;
        float x;
        if (l == 0) {
            int fi = kg >> 6, fj = kg & 63;
            x = (fj > fi && fj < F0N) ? 2.0f * f[(fi * F0N + fj) * 128 + n] : 0.0f;
        } else {
            x = f[(size_t)kg * 128 + n];
        }
        v[reg] = (_Float16)x;
    }
    *(half8*)&fprep[(size_t)l * LAYER_HALVES + (((c16 * 4 + nt) * 64 + lane) << 3)] = v;
}

// prefetch step C16 into the "next" registers
#define PREF(C16)                                                             \
    do {                                                                      \
        int c_ = (C16);                                                       \
        Bn0 = *(const half8*)(fplw + c_ * 2048);                              \
        Bn1 = *(const half8*)(fplw + c_ * 2048 + 512);                        \
        int hb_ = ((c_ & 3) << 4) + (hf << 3);                                \
        hn0 = *(const half8*)&hT[harow0 + hb_];                               \
        hn1 = *(const half8*)&hT[harow1 + hb_];                               \
        int xi_ = c_ >> 2;                                                    \
        xn0 = xs[xrow0 + xi_];                                                \
        xn1 = xs[xrow1 + xi_];                                                \
    } while (0)

#define COMPUTE()                                                             \
    do {                                                                      \
        half8 Af0 = hc0 * xc0;                                                \
        half8 Af1 = hc1 * xc1;                                                \
        acc00 = __builtin_amdgcn_mfma_f32_32x32x16_f16(Af0, Bc0, acc00, 0, 0, 0); \
        acc01 = __builtin_amdgcn_mfma_f32_32x32x16_f16(Af0, Bc1, acc01, 0, 0, 0); \
        acc10 = __builtin_amdgcn_mfma_f32_32x32x16_f16(Af1, Bc0, acc10, 0, 0, 0); \
        acc11 = __builtin_amdgcn_mfma_f32_32x32x16_f16(Af1, Bc1, acc11, 0, 0, 0); \
    } while (0)

#define ROT()                                                                 \
    do {                                                                      \
        Bc0 = Bn0; Bc1 = Bn1; hc0 = hn0; hc1 = hn1; xc0 = xn0; xc1 = xn1;     \
    } while (0)

// Epilogue for one 32x32 acc tile: TT = n-tile (0/1), NB0 = base batch.
#define EPILOGUE_TILE(ACC, TT, NB0, CM0, CM1)                                 \
    do {                                                                      \
        float r[16];                                                          \
        _Pragma("unroll")                                                     \
        for (int reg = 0; reg < 16; ++reg)                                    \
            r[reg] = fmaxf((ACC)[reg], 0.0f);                                 \
        if (layer < 2 && ng == 0) {                                           \
            const int j = (TT) * 32 + lane5;                                  \
            _Pragma("unroll")                                                 \
            for (int reg = 0; reg < 16; ++reg) {                              \
                int nb = (NB0) + (reg >> 3);                                  \
                int d  = (reg & 3) + 8 * ((reg >> 2) & 1) + 4 * hf;           \
                hT[(nb * 16 + d) * 72 + j] = (_Float16)r[reg];                \
            }                                                                 \
        }                                                                     \
        if (layer == 2 || ng == 1) {                                          \
            const float w = 1.0f + wnn[catbase + (ng * 2 + (TT)) * 32 + lane5]; \
            float s0 = ((r[0] + r[1]) + (r[2] + r[3])) +                      \
                       ((r[4] + r[5]) + (r[6] + r[7]));                       \
            float s1 = ((r[8] + r[9]) + (r[10] + r[11])) +                    \
                       ((r[12] + r[13]) + (r[14] + r[15]));                   \
            s0 += __shfl_xor(s0, 32, 64);                                     \
            s1 += __shfl_xor(s1, 32, 64);                                     \
            CM0 = fmaf(s0, w, CM0);                                           \
            CM1 = fmaf(s1, w, CM1);                                           \
        }                                                                     \
    } while (0)

__global__ __launch_bounds__(256, 3) void cin_mfma(
    const float* __restrict__ xin,     // (B, 624) fp32
    const _Float16* __restrict__ fprep,
    const float* __restrict__ wnn,     // (256)
    const float* __restrict__ bnn,     // (1)
    float* __restrict__ out)           // (B)
{
    __shared__ _Float16 hT[8 * 16 * 72] __attribute__((aligned(16)));  // [nb][d][j pad72] 18432 B
    __shared__ _Float16 xs[8 * 16 * 40] __attribute__((aligned(16)));  // [nb][d][i pad40] 10240 B
    __shared__ float outacc[8];

    const int t     = threadIdx.x;
    const int wave  = t >> 6;        // 0..3
    const int lane  = t & 63;
    const int hf    = lane >> 5;     // k-half within 16-chunk
    const int lane5 = lane & 31;
    const int dl    = lane & 15;     // d for A-side
    const int bt    = lane5 >> 4;    // A-side batch within 32-row m-tile
    const int mg    = wave >> 1;     // m-group: batches mg*4 .. +4
    const int ng    = wave & 1;      // n-half:  cols ng*64 .. +64
    const int b0    = blockIdx.x * 8;

    // zero hT (j-pad must be 0)
    for (int u = t; u < 1152; u += 256) ((uint4*)hT)[u] = uint4{0, 0, 0, 0};
    if (t < 8) outacc[t] = 0.0f;
    __syncthreads();

    // stage x0 -> hT (layer-0 hidden, [nb][d][j=i]) and xs ([nb][d][i])
    for (int u = t; u < 8 * F0N; u += 256) {
        int nb = u / F0N;
        int i  = u - nb * F0N;
        const float* src = xin + (size_t)(b0 + nb) * 624 + i * 16;
        #pragma unroll
        for (int q = 0; q < 4; ++q) {
            float4 v = *(const float4*)(src + q * 4);
            int d = q * 4;
            hT[(nb * 16 + d + 0) * 72 + i] = (_Float16)v.x;
            hT[(nb * 16 + d + 1) * 72 + i] = (_Float16)v.y;
            hT[(nb * 16 + d + 2) * 72 + i] = (_Float16)v.z;
            hT[(nb * 16 + d + 3) * 72 + i] = (_Float16)v.w;
            xs[(nb * 16 + d + 0) * 40 + i] = (_Float16)v.x;
            xs[(nb * 16 + d + 1) * 40 + i] = (_Float16)v.y;
            xs[(nb * 16 + d + 2) * 40 + i] = (_Float16)v.z;
            xs[(nb * 16 + d + 3) * 40 + i] = (_Float16)v.w;
        }
    }
    __syncthreads();

    // lane's two A-rows (m-tiles 0,1): batches mg*4 + mt*2 + bt, d = dl
    const int arow0  = (mg * 4 + bt) * 16 + dl;
    const int arow1  = (mg * 4 + 2 + bt) * 16 + dl;
    const int harow0 = arow0 * 72;
    const int harow1 = arow1 * 72;
    const int xrow0  = arow0 * 40;
    const int xrow1  = arow1 * 40;

    for (int layer = 0; layer < 3; ++layer) {
        f32x16 acc00, acc01, acc10, acc11;
        #pragma unroll
        for (int e = 0; e < 16; ++e) {
            acc00[e] = 0.0f; acc01[e] = 0.0f;
            acc10[e] = 0.0f; acc11[e] = 0.0f;
        }

        // wave's B base folds ng n-tiles + lane; frag (c16,tt) at
        // fplw + c16*2048 + tt*512 (halves)
        const _Float16* fplw = fprep + (size_t)layer * LAYER_HALVES
                             + ng * 1024 + (lane << 3);

        half8 Bc0, Bc1, hc0, hc1, Bn0, Bn1, hn0, hn1;
        _Float16 xc0, xc1, xn0, xn1;

        if (layer == 0) {
            PREF(l0_sched[0]);
            ROT();
            for (int s = 1; s < 84; ++s) {
                PREF(l0_sched[s]);
                COMPUTE();
                ROT();
            }
            COMPUTE();
        } else {
            PREF(0);
            ROT();
            for (int c = 1; c < NC16; ++c) {
                PREF(c);
                COMPUTE();
                ROT();
            }
            COMPUTE();
        }

        __syncthreads();   // all hT reads of this layer done before overwrite

        // ---- epilogue ----
        // C/D layout: col n = (ng*2+tt)*32 + lane5;
        // row = (reg&3) + 8*(reg>>2) + 4*hf -> batch_in_tile = reg>>3,
        // d = (reg&3) + 8*((reg>>2)&1) + 4*hf.
        const int catbase = (layer == 2) ? 128 : ((layer == 0) ? -64 : 0);
        {   // m-tile 0: batches mg*4, mg*4+1
            const int nb0 = mg * 4;
            float cm0 = 0.0f, cm1 = 0.0f;
            EPILOGUE_TILE(acc00, 0, nb0, cm0, cm1);
            EPILOGUE_TILE(acc01, 1, nb0, cm0, cm1);
            #pragma unroll
            for (int sh = 16; sh >= 1; sh >>= 1) {
                cm0 += __shfl_xor(cm0, sh, 64);
                cm1 += __shfl_xor(cm1, sh, 64);
            }
            if (lane == 0 && (layer == 2 || ng == 1)) {
                atomicAdd(&outacc[nb0], cm0);
                atomicAdd(&outacc[nb0 + 1], cm1);
            }
        }
        {   // m-tile 1: batches mg*4+2, mg*4+3
            const int nb0 = mg * 4 + 2;
            float cm0 = 0.0f, cm1 = 0.0f;
            EPILOGUE_TILE(acc10, 0, nb0, cm0, cm1);
            EPILOGUE_TILE(acc11, 1, nb0, cm0, cm1);
            #pragma unroll
            for (int sh = 16; sh >= 1; sh >>= 1) {
                cm0 += __shfl_xor(cm0, sh, 64);
                cm1 += __shfl_xor(cm1, sh, 64);
            }
            if (lane == 0 && (layer == 2 || ng == 1)) {
                atomicAdd(&outacc[nb0], cm0);
                atomicAdd(&outacc[nb0 + 1], cm1);
            }
        }
        __syncthreads();   // hT(next hidden) + outacc visible
    }

    if (t < 8) out[b0 + t] = outacc[t] + bnn[0];
}

extern "C" void kernel_launch(void* const* d_in, const int* in_sizes, int n_in,
                              void* d_out, int out_size, void* d_ws, size_t ws_size,
                              hipStream_t stream) {
    const float* xin = (const float*)d_in[0];
    const float* f0g = (const float*)d_in[1];
    const float* f1g = (const float*)d_in[2];
    const float* f2g = (const float*)d_in[3];
    const float* wnn = (const float*)d_in[4];
    const float* bnn = (const float*)d_in[5];
    float* out = (float*)d_out;
    _Float16* fprep = (_Float16*)d_ws;   // 3 * 319488 * 2 B = 1.83 MB

    prep_kernel<<<3 * NC16, 256, 0, stream>>>(f0g, f1g, f2g, fprep);

    const int B = in_sizes[0] / 624;     // 8192
    cin_mfma<<<B / 8, 256, 0, stream>>>(xin, fprep, wnn, bnn, out);
}